// Round 7
// baseline (68.879 us; speedup 1.0000x reference)
//
#include <hip/hip_runtime.h>
#include <hip/hip_bf16.h>
#include <cmath>
#include <cstdint>

#define Bsz   4096
#define INsz  512
#define OUTsz 512
#define NRING 16
#define KTOT  8704          /* IN*(NR+1): residual folded in as 17th slot */
#define SPLITK 8
#define NPH   17            /* 17 rings (incl residual), K=64 (the split's 64 i's) */

using short8 = __attribute__((ext_vector_type(8))) short;
using f32x4  = __attribute__((ext_vector_type(4))) float;

struct RC {
  float Cr[NRING];    // cos(2*pi*rev0_r)
  float Snr[NRING];   // -sin(2*pi*rev0_r)
  float K2, SQ, pad0, pad1;  // h=K2*xc*rcp(wl); A' = rcp(cph + SQ)
};

__device__ __forceinline__ unsigned short f2bf(float f) {
  __hip_bfloat16 h = __float2bfloat16(f);               // native cvt (RNE)
  return *reinterpret_cast<unsigned short*>(&h);
}
__device__ __forceinline__ float bf2f(unsigned short u) {
  union { unsigned int u; float f; } v; v.u = (unsigned int)u << 16;
  return v.f;
}
__device__ __forceinline__ float fastrcp(float x) {
#if __has_builtin(__builtin_amdgcn_rcpf)
  return __builtin_amdgcn_rcpf(x);
#else
  return 1.0f / x;
#endif
}
__device__ __forceinline__ float fastfract(float x) {
#if __has_builtin(__builtin_amdgcn_fractf)
  return __builtin_amdgcn_fractf(x);
#else
  return x - floorf(x);
#endif
}
__device__ __forceinline__ float cos2pi(float fr) {
#if __has_builtin(__builtin_amdgcn_cosf)
  return __builtin_amdgcn_cosf(fr);
#else
  return __cosf(fr * 6.28318530717958647692f);
#endif
}
__device__ __forceinline__ float sin2pi(float fr) {
#if __has_builtin(__builtin_amdgcn_sinf)
  return __builtin_amdgcn_sinf(fr);
#else
  return __sinf(fr * 6.28318530717958647692f);
#endif
}

__device__ __forceinline__ void gl_lds16(const void* g, void* l) {
  __builtin_amdgcn_global_load_lds(
      (const __attribute__((address_space(1))) void*)g,
      (__attribute__((address_space(3))) void*)l, 16, 0, 0);
}

// ---- pack B'^T: [OUT][KTOT] bf16, k = n*512 + i; also bias[o] = sum coeffs ----
__global__ __launch_bounds__(512) void pack_b_kernel(
    const float* __restrict__ coeffs, const float* __restrict__ bw,
    unsigned short* __restrict__ Bt, float* __restrict__ bias, float PQ) {
  __shared__ float red[8];
  const int o = blockIdx.x;        // 512 blocks
  const int i = threadIdx.x;       // 512 threads
  const float* cp = coeffs + ((size_t)i * OUTsz + o) * NRING;  // 64B contiguous
  unsigned short* row = Bt + (size_t)o * KTOT + i;
  float s = 0.0f;
#pragma unroll
  for (int j = 0; j < 4; ++j) {
    f32x4 v = *reinterpret_cast<const f32x4*>(cp + j * 4);
#pragma unroll
    for (int e = 0; e < 4; ++e) {
      const int n = j * 4 + e;
      s += v[e];
      row[(size_t)n * INsz] = f2bf(PQ * v[e]);
    }
  }
  row[(size_t)NRING * INsz] = f2bf(bw[(size_t)i * OUTsz + o]);  // residual unscaled
#pragma unroll
  for (int off = 32; off > 0; off >>= 1) s += __shfl_down(s, off);
  const int w = i >> 6;
  if ((i & 63) == 0) red[w] = s;
  __syncthreads();
  if (i == 0) {
    float t = 0.0f;
#pragma unroll
    for (int k = 0; k < 8; ++k) t += red[k];
    bias[o] = t;
  }
}

// ---- fused basis-gen + split-K bf16 MFMA GEMM ----
// BM=128 x BN=128, splitK=8 (block owns 64 i's), 8 waves, 80KB LDS
// -> 2 blocks/CU (launch_bounds(512,4), VGPR<=128). 17 phases (1 ring each,
// K=64), single barrier/phase, counted vmcnt(2), bf16 partials.
__global__ __launch_bounds__(512, 4) void gemm_fused_kernel(
    const float* __restrict__ x, const unsigned short* __restrict__ Bt,
    unsigned short* __restrict__ part, RC rc) {
  extern __shared__ char smem[];
  char* smA = smem;            // 2 x 16384
  char* smB = smem + 32768;    // 3 x 16384
  const int tid  = threadIdx.x;
  const int lane = tid & 63;
  const int w    = tid >> 6;
  const int bid  = blockIdx.x;
  const int combo = bid & 31;        // same combo -> same XCD (32 = 0 mod 8)
  const int rb   = bid >> 5;         // 0..31
  const int cb   = combo & 3, ks = combo >> 2;   // cb 0..3, ks 0..7
  const int brow = rb * 128, bcol = cb * 128;

  // --- A-gen ownership: row r (0..127), i-quarter q4 (16 of the 64 i's) ---
  const int r  = tid & 127;
  const int q4 = tid >> 7;           // 0..3
  const int wb0 = r * 128 + (((q4 * 2 + 0) ^ (r & 7)) * 16);
  const int wb1 = r * 128 + (((q4 * 2 + 1) ^ (r & 7)) * 16);

  // --- B staging: pre-swizzled per-lane global source, linear LDS dest ---
  const int cg = (lane & 7) ^ ((lane >> 3) & 7);
  const unsigned short* gb0 = Bt + (size_t)(bcol + w * 8 + (lane >> 3)) * KTOT
                                 + ks * 64 + cg * 8;

  // --- fragment read geometry: 8 waves = 2M x 4N, wave tile 64x32 ---
  const int wr = w >> 2, wc = w & 3;
  const int l7 = lane & 7;
  const int rowA = wr * 64 + (lane & 15);
  const int rowB = wc * 32 + (lane & 15);

  // --- prologue: 16 x-values, trig, residual bf16 pack ---
  float cth[16], sth[16];
  short8 xbfa, xbfb;
  {
    float xf[16];
    const float* gx = x + (size_t)(brow + r) * INsz + ks * 64 + q4 * 16;
#pragma unroll
    for (int j = 0; j < 4; ++j) {
      f32x4 v = *reinterpret_cast<const f32x4*>(gx + j * 4);
#pragma unroll
      for (int e = 0; e < 4; ++e) xf[j * 4 + e] = v[e];
    }
#pragma unroll
    for (int c = 0; c < 8; ++c) {
      xbfa[c] = (short)f2bf(xf[c]);
      xbfb[c] = (short)f2bf(xf[c + 8]);
    }
#pragma unroll
    for (int c = 0; c < 16; ++c) {
      float xc = fminf(fmaxf(xf[c], -1.0f), 1.0f);
      float wl = __builtin_fmaf(xc, 4.0e-9f, 1550.0e-9f);
      float hh = rc.K2 * xc * fastrcp(wl);
      float fr = fastfract(hh);
      cth[c] = cos2pi(fr);
      sth[c] = sin2pi(fr);
    }
  }

  auto STAGE = [&](int p) {   // 2 gl_lds (2 x 64 B-rows) for ring p
    char* ldst = smB + (p % 3) * 16384 + w * 1024;
    const unsigned short* src = gb0 + (size_t)p * 512;
    gl_lds16(src, ldst);
    gl_lds16(src + (size_t)64 * KTOT, ldst + 8192);
  };
  auto GENA = [&](int p) {    // generate A-tile (ring p) into As[p&1]
    char* dst = smA + (p & 1) * 16384;
    if (p < NRING) {
      const float Crn = rc.Cr[p], Snn = rc.Snr[p];
#pragma unroll
      for (int g = 0; g < 2; ++g) {
        short8 wv;
#pragma unroll
        for (int e = 0; e < 8; ++e) {
          float cph = __builtin_fmaf(cth[g * 8 + e], Crn, sth[g * 8 + e] * Snn);
          wv[e] = (short)f2bf(fastrcp(cph + rc.SQ));
        }
        *reinterpret_cast<short8*>(dst + (g ? wb1 : wb0)) = wv;
      }
    } else {                  // residual ring: raw (unclipped) x, pre-packed
      *reinterpret_cast<short8*>(dst + wb0) = xbfa;
      *reinterpret_cast<short8*>(dst + wb1) = xbfb;
    }
  };

  f32x4 acc[4][2];
#pragma unroll
  for (int m = 0; m < 4; ++m)
#pragma unroll
    for (int q = 0; q < 2; ++q) acc[m][q] = (f32x4){0.f, 0.f, 0.f, 0.f};

  STAGE(0); STAGE(1);
  GENA(0);
  asm volatile("s_waitcnt vmcnt(2) lgkmcnt(0)" ::: "memory");
  __builtin_amdgcn_s_barrier();
  __builtin_amdgcn_sched_barrier(0);

#pragma unroll
  for (int p = 0; p < NPH; ++p) {
    if (p + 2 < NPH) STAGE(p + 2);
    if (p + 1 < NPH) GENA(p + 1);
    const char* bA = smA + (p & 1) * 16384;
    const char* bB = smB + (p % 3) * 16384;
#pragma unroll
    for (int kk = 0; kk < 2; ++kk) {
      const int oct = (((lane >> 4) + kk * 4) ^ l7) * 16;
      short8 af[4], bfr[2];
#pragma unroll
      for (int m = 0; m < 4; ++m)
        af[m] = *reinterpret_cast<const short8*>(bA + (rowA + m * 16) * 128 + oct);
#pragma unroll
      for (int q = 0; q < 2; ++q)
        bfr[q] = *reinterpret_cast<const short8*>(bB + (rowB + q * 16) * 128 + oct);
      __builtin_amdgcn_s_setprio(1);
#pragma unroll
      for (int m = 0; m < 4; ++m)
#pragma unroll
        for (int q = 0; q < 2; ++q)
          acc[m][q] = __builtin_amdgcn_mfma_f32_16x16x32_bf16(af[m], bfr[q], acc[m][q], 0, 0, 0);
      __builtin_amdgcn_s_setprio(0);
    }
    if (p + 1 < NPH) {
      if (p + 2 < NPH) {
        asm volatile("s_waitcnt vmcnt(2) lgkmcnt(0)" ::: "memory");  // S(p+1) landed
      } else {
        asm volatile("s_waitcnt vmcnt(0) lgkmcnt(0)" ::: "memory");  // drain last
      }
      __builtin_amdgcn_s_barrier();
      __builtin_amdgcn_sched_barrier(0);
    }
  }

  // epilogue: bf16 partials
  unsigned short* po = part + (size_t)ks * ((size_t)Bsz * OUTsz);
  const int r0 = brow + wr * 64 + ((lane >> 4) * 4);
  const int c0 = bcol + wc * 32 + (lane & 15);
#pragma unroll
  for (int m = 0; m < 4; ++m)
#pragma unroll
    for (int q = 0; q < 2; ++q)
#pragma unroll
      for (int e = 0; e < 4; ++e)
        po[(size_t)(r0 + m * 16 + e) * OUTsz + (c0 + q * 16)] = f2bf(acc[m][q][e]);
}

// ---- reduce 8 bf16 split-K partials + bias + kl ----
__global__ __launch_bounds__(256) void reduce_kernel(
    const unsigned short* __restrict__ part, const float* __restrict__ bias,
    float* __restrict__ out) {
  const size_t idx  = (size_t)blockIdx.x * 256 + threadIdx.x;  // unit = 8 outputs
  const size_t base = idx * 8;
  float s[8];
#pragma unroll
  for (int e = 0; e < 8; ++e) s[e] = 0.0f;
#pragma unroll
  for (int sp = 0; sp < SPLITK; ++sp) {
    short8 v = *reinterpret_cast<const short8*>(part + sp * ((size_t)Bsz * OUTsz) + base);
#pragma unroll
    for (int e = 0; e < 8; ++e) s[e] += bf2f((unsigned short)v[e]);
  }
  const int ob = (int)(base & (OUTsz - 1));
  f32x4 b0 = *reinterpret_cast<const f32x4*>(bias + ob);
  f32x4 b1 = *reinterpret_cast<const f32x4*>(bias + ob + 4);
  f32x4 o0 = { s[0] + b0[0], s[1] + b0[1], s[2] + b0[2], s[3] + b0[3] };
  f32x4 o1 = { s[4] + b1[0], s[5] + b1[1], s[6] + b1[2], s[7] + b1[3] };
  *reinterpret_cast<f32x4*>(out + base) = o0;
  *reinterpret_cast<f32x4*>(out + base + 4) = o1;
  if (idx == 0) out[(size_t)Bsz * OUTsz] = 0.0f;   // kl
}

extern "C" void kernel_launch(void* const* d_in, const int* in_sizes, int n_in,
                              void* d_out, int out_size, void* d_ws, size_t ws_size,
                              hipStream_t stream) {
  const float* x      = (const float*)d_in[0];
  const float* coeffs = (const float*)d_in[1];
  const float* bw     = (const float*)d_in[2];
  float* out = (float*)d_out;

  unsigned short* Bt   = (unsigned short*)d_ws;                            // 8,912,896 B
  unsigned short* part = (unsigned short*)((char*)d_ws + (size_t)OUTsz * KTOT * 2);  // 33,554,432 B
  float* bias = (float*)((char*)d_ws + (size_t)OUTsz * KTOT * 2
                                     + (size_t)SPLITK * Bsz * OUTsz * 2);  // 2048 B

  RC rc;
  float PQ;
  {
    const double PI  = 3.14159265358979323846;
    const double Lc  = 2.0 * PI * 30.0e-6;
    const double WL0 = 1550.0e-9;
    const double NG  = 4.2;
    const double Aamp = pow(10.0, -3.0 * (Lc * 100.0) / 20.0);
    const double Rt2  = 0.8;
    const double Rt   = sqrt(Rt2);
    for (int rr = 0; rr < NRING; ++rr) {
      double off  = -PI + rr * (2.0 * PI / 15.0);
      double neff = 2.34 + off * WL0 / (2.0 * PI * Lc);
      double rev0 = (Lc / WL0) * neff;
      rc.Cr[rr]  = (float)cos(2.0 * PI * rev0);
      rc.Snr[rr] = (float)(-sin(2.0 * PI * rev0));
    }
    const double qn = -2.0 * Rt * Aamp;
    const double s  = 1.0 + Rt2 * Aamp * Aamp;
    const double P  = -(1.0 - Aamp * Aamp) * (1.0 - Rt2);
    rc.K2 = (float)(-4.0e-9 * Lc * NG / WL0);
    rc.SQ = (float)(s / qn);
    rc.pad0 = rc.pad1 = 0.f;
    PQ = (float)(P / qn);
  }

  hipFuncSetAttribute(reinterpret_cast<const void*>(gemm_fused_kernel),
                      hipFuncAttributeMaxDynamicSharedMemorySize, 81920);

  hipLaunchKernelGGL(pack_b_kernel, dim3(OUTsz), dim3(512), 0, stream,
                     coeffs, bw, Bt, bias, PQ);
  hipLaunchKernelGGL(gemm_fused_kernel, dim3(1024), dim3(512), 81920, stream,
                     x, Bt, part, rc);
  hipLaunchKernelGGL(reduce_kernel, dim3((Bsz * OUTsz / 8) / 256), dim3(256), 0, stream,
                     part, bias, out);
}

// Round 8
// 64.542 us; speedup vs baseline: 1.0672x; 1.0672x over previous
//
#include <hip/hip_runtime.h>
#include <hip/hip_bf16.h>
#include <cmath>
#include <cstdint>

#define Bsz   4096
#define INsz  512
#define OUTsz 512
#define NRING 16
#define KTOT  8704          /* IN*(NR+1): residual folded in as 17th slot */
#define SPLITK 4
#define NPH   34            /* 2 i-halves x 17 rings, K=64 each */

using short8 = __attribute__((ext_vector_type(8))) short;
using f32x4  = __attribute__((ext_vector_type(4))) float;

struct RC {
  float Cr[NRING];    // cos(2*pi*rev0_r)
  float Snr[NRING];   // -sin(2*pi*rev0_r)
  float K2, SQ, pad0, pad1;  // h=K2*xc*rcp(wl); A' = rcp(cph + SQ)
};

__device__ __forceinline__ unsigned short f2bf(float f) {
  __hip_bfloat16 h = __float2bfloat16(f);               // native cvt (RNE)
  return *reinterpret_cast<unsigned short*>(&h);
}
__device__ __forceinline__ float fastrcp(float x) {
#if __has_builtin(__builtin_amdgcn_rcpf)
  return __builtin_amdgcn_rcpf(x);
#else
  return 1.0f / x;
#endif
}
__device__ __forceinline__ float fastfract(float x) {
#if __has_builtin(__builtin_amdgcn_fractf)
  return __builtin_amdgcn_fractf(x);
#else
  return x - floorf(x);
#endif
}
__device__ __forceinline__ float cos2pi(float fr) {
#if __has_builtin(__builtin_amdgcn_cosf)
  return __builtin_amdgcn_cosf(fr);
#else
  return __cosf(fr * 6.28318530717958647692f);
#endif
}
__device__ __forceinline__ float sin2pi(float fr) {
#if __has_builtin(__builtin_amdgcn_sinf)
  return __builtin_amdgcn_sinf(fr);
#else
  return __sinf(fr * 6.28318530717958647692f);
#endif
}

__device__ __forceinline__ void gl_lds16(const void* g, void* l) {
  __builtin_amdgcn_global_load_lds(
      (const __attribute__((address_space(1))) void*)g,
      (__attribute__((address_space(3))) void*)l, 16, 0, 0);
}

// ---- pack B'^T: [OUT][KTOT] bf16, k = n*512 + i; also bias[o] = sum coeffs ----
__global__ __launch_bounds__(512) void pack_b_kernel(
    const float* __restrict__ coeffs, const float* __restrict__ bw,
    unsigned short* __restrict__ Bt, float* __restrict__ bias, float PQ) {
  __shared__ float red[8];
  const int o = blockIdx.x;        // 512 blocks
  const int i = threadIdx.x;       // 512 threads
  const float* cp = coeffs + ((size_t)i * OUTsz + o) * NRING;  // 64B contiguous
  unsigned short* row = Bt + (size_t)o * KTOT + i;
  float s = 0.0f;
#pragma unroll
  for (int j = 0; j < 4; ++j) {
    f32x4 v = *reinterpret_cast<const f32x4*>(cp + j * 4);
#pragma unroll
    for (int e = 0; e < 4; ++e) {
      const int n = j * 4 + e;
      s += v[e];
      row[(size_t)n * INsz] = f2bf(PQ * v[e]);
    }
  }
  row[(size_t)NRING * INsz] = f2bf(bw[(size_t)i * OUTsz + o]);  // residual unscaled
#pragma unroll
  for (int off = 32; off > 0; off >>= 1) s += __shfl_down(s, off);
  const int w = i >> 6;
  if ((i & 63) == 0) red[w] = s;
  __syncthreads();
  if (i == 0) {
    float t = 0.0f;
#pragma unroll
    for (int k = 0; k < 8; ++k) t += red[k];
    bias[o] = t;
  }
}

// ---- fused basis-gen + split-K GEMM with producer/consumer wave split ----
// 1024 thr = 16 waves: w0-7 producers (trig+GENA+B-staging), w8-15 consumers
// (ds_read+MFMA only). BM=128 x BN=256, splitK=4, grid 256 = 1 block/CU.
// LDS: As[2][128][64] 32KB + Bs[3][256][64] 96KB = 128KB.
// Producers: counted vmcnt(4) + raw s_barrier (prefetch crosses barriers).
// Consumers: __syncthreads() (fence stops LDS-read hoisting; no vmem to drain).
__global__ __launch_bounds__(1024) void gemm_fused_kernel(
    const float* __restrict__ x, const unsigned short* __restrict__ Bt,
    float* __restrict__ part, RC rc) {
  extern __shared__ char smem[];
  char* smA = smem;            // 2 x 16384
  char* smB = smem + 32768;    // 3 x 32768
  const int tid  = threadIdx.x;
  const int lane = tid & 63;
  const int w    = tid >> 6;
  const int bid  = blockIdx.x;
  const int combo = bid & 7;         // same (cb,ks) -> same XCD (L2-resident Bt slice)
  const int rb   = bid >> 3;         // 0..31
  const int cb   = combo & 1, ks = combo >> 1;
  const int brow = rb * 128, bcol = cb * 256;

  if (w < 8) {
    // ================= PRODUCER (512 threads) =================
    const int r  = tid & 127;        // A row 0..127
    const int q4 = tid >> 7;         // i-quarter 0..3 (16 i's each)
    const int wb0 = r * 128 + (((q4 * 2 + 0) ^ (r & 7)) * 16);
    const int wb1 = r * 128 + (((q4 * 2 + 1) ^ (r & 7)) * 16);
    const int cg = (lane & 7) ^ ((lane >> 3) & 7);   // pre-swizzled B source octet
    const unsigned short* gb0 = Bt + (size_t)(bcol + w * 8 + (lane >> 3)) * KTOT
                                   + ks * 128 + cg * 8;

    auto STAGE = [&](int p, int slot) {   // 4 gl_lds: 256 B-rows of tile p
      const int is = (p >= 17) ? 1 : 0;
      const int n  = p - 17 * is;
      char* ldst = smB + slot * 32768 + w * 1024;
      const unsigned short* src = gb0 + n * 512 + is * 64;
#pragma unroll
      for (int iss = 0; iss < 4; ++iss)
        gl_lds16(src + (size_t)iss * 64 * KTOT, ldst + iss * 8192);
    };

    // x loads first, then stage 0/1 (trig VALU hides the load latency)
    float xf0[16], xf1[16];
    {
      const float* gx = x + (size_t)(brow + r) * INsz + ks * 128 + q4 * 16;
#pragma unroll
      for (int j = 0; j < 4; ++j) {
        f32x4 v0 = *reinterpret_cast<const f32x4*>(gx + j * 4);
        f32x4 v1 = *reinterpret_cast<const f32x4*>(gx + 64 + j * 4);
#pragma unroll
        for (int e = 0; e < 4; ++e) { xf0[j*4+e] = v0[e]; xf1[j*4+e] = v1[e]; }
      }
    }
    STAGE(0, 0); STAGE(1, 1);

    short8 x0a, x0b, x1a, x1b;
#pragma unroll
    for (int c = 0; c < 8; ++c) {
      x0a[c] = (short)f2bf(xf0[c]);   x0b[c] = (short)f2bf(xf0[c + 8]);
      x1a[c] = (short)f2bf(xf1[c]);   x1b[c] = (short)f2bf(xf1[c + 8]);
    }
    float cth0[16], sth0[16], cth1[16], sth1[16];
#pragma unroll
    for (int c = 0; c < 16; ++c) {
      float xc = fminf(fmaxf(xf0[c], -1.0f), 1.0f);
      float wl = __builtin_fmaf(xc, 4.0e-9f, 1550.0e-9f);
      float fr = fastfract(rc.K2 * xc * fastrcp(wl));
      cth0[c] = cos2pi(fr);  sth0[c] = sin2pi(fr);
    }
#pragma unroll
    for (int c = 0; c < 16; ++c) {
      float xc = fminf(fmaxf(xf1[c], -1.0f), 1.0f);
      float wl = __builtin_fmaf(xc, 4.0e-9f, 1550.0e-9f);
      float fr = fastfract(rc.K2 * xc * fastrcp(wl));
      cth1[c] = cos2pi(fr);  sth1[c] = sin2pi(fr);
    }

    auto GEN = [&](char* dst, int ring, const float (&ct)[16], const float (&st)[16],
                   short8 xa, short8 xb, float Crn, float Snn) {
      if (ring < NRING) {
#pragma unroll
        for (int g = 0; g < 2; ++g) {
          short8 wv;
#pragma unroll
          for (int e = 0; e < 8; ++e) {
            float cph = __builtin_fmaf(ct[g * 8 + e], Crn, st[g * 8 + e] * Snn);
            wv[e] = (short)f2bf(fastrcp(cph + rc.SQ));
          }
          *reinterpret_cast<short8*>(dst + (g ? wb1 : wb0)) = wv;
        }
      } else {
        *reinterpret_cast<short8*>(dst + wb0) = xa;
        *reinterpret_cast<short8*>(dst + wb1) = xb;
      }
    };

    GEN(smA, 0, cth0, sth0, x0a, x0b, rc.Cr[0], rc.Snr[0]);   // tile 0
    asm volatile("s_waitcnt vmcnt(4) lgkmcnt(0)" ::: "memory");
    __builtin_amdgcn_s_barrier();
    __builtin_amdgcn_sched_barrier(0);

    int slotS = 2;   // STAGE(p+2) slot, (p+2)%3
    int bufG  = 1;   // GENA(p+1) buffer, (p+1)&1
#pragma unroll 1
    for (int p = 0; p < 16; ++p) {             // produce tiles 1..16 (is=0)
      const int ring = p + 1;                  // ring 16 = residual
      GEN(smA + bufG * 16384, ring, cth0, sth0, x0a, x0b,
          rc.Cr[ring & 15], rc.Snr[ring & 15]);
      STAGE(p + 2, slotS);
      slotS = (slotS == 2) ? 0 : slotS + 1;
      bufG ^= 1;
      asm volatile("s_waitcnt vmcnt(4) lgkmcnt(0)" ::: "memory");
      __builtin_amdgcn_s_barrier();
      __builtin_amdgcn_sched_barrier(0);
    }
#pragma unroll 1
    for (int p = 16; p < 33; ++p) {            // produce tiles 17..33 (is=1)
      const int ring = p - 16;                 // 0..16 (16 = residual)
      GEN(smA + bufG * 16384, ring, cth1, sth1, x1a, x1b,
          rc.Cr[ring & 15], rc.Snr[ring & 15]);
      if (p + 2 < NPH) {
        STAGE(p + 2, slotS);
        slotS = (slotS == 2) ? 0 : slotS + 1;
        asm volatile("s_waitcnt vmcnt(4) lgkmcnt(0)" ::: "memory");
      } else {
        asm volatile("s_waitcnt vmcnt(0) lgkmcnt(0)" ::: "memory");
      }
      bufG ^= 1;
      __builtin_amdgcn_s_barrier();
      __builtin_amdgcn_sched_barrier(0);
    }
    __builtin_amdgcn_s_barrier();              // phase 33 (consumers compute)
  } else {
    // ================= CONSUMER (512 threads, 8 waves = 2M x 4N) =============
    const int cw = w - 8;
    const int wr = cw >> 2, wc = cw & 3;       // wave tile 64x64
    const int l7 = lane & 7;
    const int rowA = wr * 64 + (lane & 15);
    const int rowB = wc * 64 + (lane & 15);
    const int oct0 = (((lane >> 4) + 0) ^ l7) * 16;
    const int oct1 = (((lane >> 4) + 4) ^ l7) * 16;

    f32x4 acc[4][4];
#pragma unroll
    for (int m = 0; m < 4; ++m)
#pragma unroll
      for (int q = 0; q < 4; ++q) acc[m][q] = (f32x4){0.f, 0.f, 0.f, 0.f};

    __syncthreads();                           // matches producer prologue barrier

    int slotB = 0, bufA = 0;
#pragma unroll 1
    for (int p = 0; p < NPH; ++p) {
      const char* bA = smA + bufA * 16384;
      const char* bB = smB + slotB * 32768;
#pragma unroll
      for (int kk = 0; kk < 2; ++kk) {
        const int oct = kk ? oct1 : oct0;
        short8 af[4], bf[4];
#pragma unroll
        for (int m = 0; m < 4; ++m)
          af[m] = *reinterpret_cast<const short8*>(bA + (rowA + m * 16) * 128 + oct);
#pragma unroll
        for (int q = 0; q < 4; ++q)
          bf[q] = *reinterpret_cast<const short8*>(bB + (rowB + q * 16) * 128 + oct);
        __builtin_amdgcn_s_setprio(1);
#pragma unroll
        for (int m = 0; m < 4; ++m)
#pragma unroll
          for (int q = 0; q < 4; ++q)
            acc[m][q] = __builtin_amdgcn_mfma_f32_16x16x32_bf16(af[m], bf[q], acc[m][q], 0, 0, 0);
        __builtin_amdgcn_s_setprio(0);
      }
      bufA ^= 1;
      slotB = (slotB == 2) ? 0 : slotB + 1;
      __syncthreads();                         // fence: no read hoisting past barrier
    }

    float* po = part + (size_t)ks * ((size_t)Bsz * OUTsz);
    const int r0 = brow + wr * 64 + ((lane >> 4) * 4);
    const int c0 = bcol + wc * 64 + (lane & 15);
#pragma unroll
    for (int m = 0; m < 4; ++m)
#pragma unroll
      for (int q = 0; q < 4; ++q)
#pragma unroll
        for (int e = 0; e < 4; ++e)
          po[(size_t)(r0 + m * 16 + e) * OUTsz + (c0 + q * 16)] = acc[m][q][e];
  }
}

// ---- reduce 4 split-K partials + bias + kl ----
__global__ __launch_bounds__(256) void reduce_kernel(
    const f32x4* __restrict__ part, const f32x4* __restrict__ bias,
    float* __restrict__ out) {
  const size_t idx = (size_t)blockIdx.x * 256 + threadIdx.x;
  const size_t stride = (size_t)Bsz * OUTsz / 4;
  f32x4 v = part[idx] + part[idx + stride] + part[idx + 2 * stride] + part[idx + 3 * stride];
  v = v + bias[idx & 127];
  reinterpret_cast<f32x4*>(out)[idx] = v;
  if (idx == 0) out[(size_t)Bsz * OUTsz] = 0.0f;   // kl
}

extern "C" void kernel_launch(void* const* d_in, const int* in_sizes, int n_in,
                              void* d_out, int out_size, void* d_ws, size_t ws_size,
                              hipStream_t stream) {
  const float* x      = (const float*)d_in[0];
  const float* coeffs = (const float*)d_in[1];
  const float* bw     = (const float*)d_in[2];
  float* out = (float*)d_out;

  unsigned short* Bt = (unsigned short*)d_ws;                              // 8,912,896 B
  float* part = (float*)((char*)d_ws + (size_t)OUTsz * KTOT * 2);          // 33,554,432 B
  float* bias = (float*)((char*)d_ws + (size_t)OUTsz * KTOT * 2
                                     + (size_t)SPLITK * Bsz * OUTsz * 4);  // 2048 B

  RC rc;
  float PQ;
  {
    const double PI  = 3.14159265358979323846;
    const double Lc  = 2.0 * PI * 30.0e-6;
    const double WL0 = 1550.0e-9;
    const double NG  = 4.2;
    const double Aamp = pow(10.0, -3.0 * (Lc * 100.0) / 20.0);
    const double Rt2  = 0.8;
    const double Rt   = sqrt(Rt2);
    for (int rr = 0; rr < NRING; ++rr) {
      double off  = -PI + rr * (2.0 * PI / 15.0);
      double neff = 2.34 + off * WL0 / (2.0 * PI * Lc);
      double rev0 = (Lc / WL0) * neff;
      rc.Cr[rr]  = (float)cos(2.0 * PI * rev0);
      rc.Snr[rr] = (float)(-sin(2.0 * PI * rev0));
    }
    const double qn = -2.0 * Rt * Aamp;
    const double s  = 1.0 + Rt2 * Aamp * Aamp;
    const double P  = -(1.0 - Aamp * Aamp) * (1.0 - Rt2);
    rc.K2 = (float)(-4.0e-9 * Lc * NG / WL0);
    rc.SQ = (float)(s / qn);
    rc.pad0 = rc.pad1 = 0.f;
    PQ = (float)(P / qn);
  }

  hipFuncSetAttribute(reinterpret_cast<const void*>(gemm_fused_kernel),
                      hipFuncAttributeMaxDynamicSharedMemorySize, 131072);

  hipLaunchKernelGGL(pack_b_kernel, dim3(OUTsz), dim3(512), 0, stream,
                     coeffs, bw, Bt, bias, PQ);
  hipLaunchKernelGGL(gemm_fused_kernel, dim3(256), dim3(1024), 131072, stream,
                     x, Bt, part, rc);
  hipLaunchKernelGGL(reduce_kernel, dim3((Bsz * OUTsz / 4) / 256), dim3(256), 0, stream,
                     (const f32x4*)part, (const f32x4*)bias, out);
}